// Round 1
// 952.776 us; speedup vs baseline: 1.0567x; 1.0567x over previous
//
#include <hip/hip_runtime.h>
#include <hip/hip_bf16.h>
#include <stdint.h>

#define SQ   1024
#define NB   8
#define HD   1024
#define NHD  16
#define DKK  64
// bh = NHD*NB = 128

typedef __bf16 bf16x8_t __attribute__((ext_vector_type(8)));
typedef __bf16 bf16x4_t __attribute__((ext_vector_type(4)));
typedef float  f32x4_t  __attribute__((ext_vector_type(4)));
typedef __hip_bfloat16 bf16;

__device__ __forceinline__ void gld_lds16(const void* g, void* l) {
    __builtin_amdgcn_global_load_lds(
        (__attribute__((address_space(1))) void*)const_cast<void*>(g),
        (__attribute__((address_space(3))) void*)l,
        16, 0, 0);
}

__device__ __forceinline__ bf16x8_t cvt8(float4 a, float4 b) {
    bf16x8_t r;
    r[0] = (__bf16)a.x; r[1] = (__bf16)a.y; r[2] = (__bf16)a.z; r[3] = (__bf16)a.w;
    r[4] = (__bf16)b.x; r[5] = (__bf16)b.y; r[6] = (__bf16)b.z; r[7] = (__bf16)b.w;
    return r;
}

// stage a 64x64 bf16 tile (64 rows x 128B) into LDS via global_load_lds,
// bank-swizzled on the SOURCE side (LDS stays linear).
__device__ __forceinline__ void stage64(const char* gbase, int rowstride,
                                        char* lbase, int w, int lane) {
#pragma unroll
    for (int q = 0; q < 2; ++q) {
        const int cid = (q * 4 + w) * 64 + lane;
        const int r   = cid >> 3;
        const int cc  = (cid & 7) ^ ((r ^ (r >> 3)) & 7);
        gld_lds16(gbase + r * rowstride + cc * 16, lbase + cid * 16);
    }
}

// ---------------------------------------------------------------------------
// GEMM: C[m,o] = sum_k A[m,k] * W[o,k]   (A: 8192x1024, W: 1024x1024)
// W always f32 (cvt-staged). mode 0: A f32, Out bf16 scatter:
//   z<2 : head-major  Out[((h*8+b)*SQ + s)*64 + d]
//   z==2: V transposed Out[((h*8+b)*64 + d)*SQ + s]
// mode 1: A bf16 (global_load_lds), Out = f32 row-major Out[m*HD + o]
// Double-buffered LDS, issue-loads-early / compute / commit / one barrier.
// ---------------------------------------------------------------------------
__global__ __launch_bounds__(256, 2)
void gemm_kernel(const void* __restrict__ A0, const void* __restrict__ A1,
                 const void* __restrict__ A2,
                 const float* __restrict__ W0, const float* __restrict__ W1,
                 const float* __restrict__ W2,
                 void* __restrict__ O0, void* __restrict__ O1,
                 void* __restrict__ O2, int mode)
{
    const int z = blockIdx.z;
    const void*  A  = (z == 0) ? A0 : (z == 1) ? A1 : A2;
    const float* Wf = (z == 0) ? W0 : (z == 1) ? W1 : W2;
    void*        Ov = (z == 0) ? O0 : (z == 1) ? O1 : O2;

    __shared__ alignas(16) bf16 lA[2][128 * 32];
    __shared__ alignas(16) bf16 lB[2][128 * 32];

    const int tid  = threadIdx.x;
    const int lane = tid & 63;
    const int w    = tid >> 6;
    const int wr   = w >> 1;
    const int wc   = w & 1;
    const int g    = lane >> 4;
    const int ln   = lane & 15;
    const int bm   = blockIdx.y;
    const int bn   = blockIdx.x;

    f32x4_t acc[4][4];
#pragma unroll
    for (int i = 0; i < 4; ++i)
#pragma unroll
        for (int j = 0; j < 4; ++j)
            acc[i][j] = (f32x4_t){0.f, 0.f, 0.f, 0.f};

    const size_t arow0 = (size_t)bm * 128;
    const size_t brow0 = (size_t)bn * 128;
    const float* Af = (const float*)A;
    const bf16*  Ab = (const bf16*)A;

    int scid[2], srow[2], sch[2];
#pragma unroll
    for (int q = 0; q < 2; ++q) {
        const int cid = (q * 4 + w) * 64 + lane;
        scid[q] = cid;
        srow[q] = cid >> 2;
        sch[q]  = (cid & 3) ^ ((srow[q] ^ (srow[q] >> 2)) & 3);   // bank swizzle
    }

    float4 pa[4], pw[4];

    auto issue_loads = [&](int k0, int buf) {
#pragma unroll
        for (int q = 0; q < 2; ++q) {
            const float4* wsrc = (const float4*)(Wf + (brow0 + srow[q]) * HD + k0 + sch[q] * 8);
            pw[q * 2]     = wsrc[0];
            pw[q * 2 + 1] = wsrc[1];
        }
        if (mode == 0) {
#pragma unroll
            for (int q = 0; q < 2; ++q) {
                const float4* asrc = (const float4*)(Af + (arow0 + srow[q]) * HD + k0 + sch[q] * 8);
                pa[q * 2]     = asrc[0];
                pa[q * 2 + 1] = asrc[1];
            }
        } else {
#pragma unroll
            for (int q = 0; q < 2; ++q)
                gld_lds16((const char*)Ab + ((arow0 + srow[q]) * HD + k0) * 2 + sch[q] * 16,
                          (char*)&lA[buf][0] + scid[q] * 16);
        }
    };
    auto commit_writes = [&](int buf) {
#pragma unroll
        for (int q = 0; q < 2; ++q)
            *(bf16x8_t*)&lB[buf][scid[q] * 8] = cvt8(pw[q * 2], pw[q * 2 + 1]);
        if (mode == 0) {
#pragma unroll
            for (int q = 0; q < 2; ++q)
                *(bf16x8_t*)&lA[buf][scid[q] * 8] = cvt8(pa[q * 2], pa[q * 2 + 1]);
        }
    };

    issue_loads(0, 0);
    commit_writes(0);
    __syncthreads();

    int cur = 0;
    for (int ks = 0; ks < 32; ++ks) {
        if (ks < 31) issue_loads((ks + 1) * 32, cur ^ 1);   // prefetch next tile
        bf16x8_t av[4], bv[4];
#pragma unroll
        for (int mi = 0; mi < 4; ++mi) {
            const int row = wr * 64 + mi * 16 + ln;
            av[mi] = *(const bf16x8_t*)&lA[cur][row * 32 + ((g ^ ((row ^ (row >> 2)) & 3)) << 3)];
        }
#pragma unroll
        for (int ni = 0; ni < 4; ++ni) {
            const int row = wc * 64 + ni * 16 + ln;
            bv[ni] = *(const bf16x8_t*)&lB[cur][row * 32 + ((g ^ ((row ^ (row >> 2)) & 3)) << 3)];
        }
#pragma unroll
        for (int mi = 0; mi < 4; ++mi)
#pragma unroll
            for (int ni = 0; ni < 4; ++ni)
                acc[mi][ni] = __builtin_amdgcn_mfma_f32_16x16x32_bf16(
                    av[mi], bv[ni], acc[mi][ni], 0, 0, 0);
        if (ks < 31) commit_writes(cur ^ 1);                // loads had MFMA phase to land
        __syncthreads();
        cur ^= 1;
    }

    bf16*  Ob = (bf16*)Ov;
    float* Of = (float*)Ov;
#pragma unroll
    for (int mi = 0; mi < 4; ++mi) {
#pragma unroll
        for (int ni = 0; ni < 4; ++ni) {
            const int o = bn * 128 + wc * 64 + ni * 16 + ln;
#pragma unroll
            for (int r = 0; r < 4; ++r) {
                const int m = bm * 128 + wr * 64 + mi * 16 + g * 4 + r;
                const float v = acc[mi][ni][r];
                if (mode == 0) {
                    const int h = o >> 6, d = o & 63;
                    const int s = m >> 3, b = m & 7;
                    if (z == 2)
                        Ob[((size_t)((h * 8 + b) * DKK + d)) * SQ + s] = __float2bfloat16(v);
                    else
                        Ob[(((size_t)(h * 8 + b) * SQ + s) << 6) + d] = __float2bfloat16(v);
                } else {
                    Of[(size_t)m * HD + o] = v;
                }
            }
        }
    }
}

// ---------------------------------------------------------------------------
// K2a: per (bh, i-block of 64): rowsum of exp(K.Q^T/8) over unmasked j,
// writes invS[bh][i] = 1/rowsum. (No max subtraction: |s| <~ 3.)
// K frags hoisted to regs; Q double-buffered, 1 barrier/tile.
// ---------------------------------------------------------------------------
__global__ __launch_bounds__(256, 2)
void rowsum_kernel(const bf16* __restrict__ Kh, const bf16* __restrict__ Qh,
                   float* __restrict__ invS)
{
    __shared__ alignas(16) bf16 Kl[64 * 64];
    __shared__ alignas(16) bf16 Ql[2][64 * 64];
    const int tid = threadIdx.x, lane = tid & 63, w = tid >> 6;
    const int g = lane >> 4, ln = lane & 15;
    const int ib = 15 - (int)blockIdx.x, bh = blockIdx.y;   // heavy blocks first
    const char* Kp = (const char*)(Kh + ((size_t)bh * SQ + ib * 64) * DKK);
    const char* Qp = (const char*)(Qh + (size_t)bh * SQ * DKK);

    stage64(Kp, 128, (char*)Kl, w, lane);
    stage64(Qp, 128, (char*)Ql[0], w, lane);
    __syncthreads();

    const int arow = w * 16 + ln;
    const int asw  = (arow ^ (arow >> 3)) & 7;
    const bf16x8_t ak0 = *(const bf16x8_t*)&Kl[arow * 64 + ((g ^ asw) << 3)];
    const bf16x8_t ak1 = *(const bf16x8_t*)&Kl[arow * 64 + (((4 + g) ^ asw) << 3)];
    const int irow = ib * 64 + w * 16 + g * 4;

    float lsum[4] = {0.f, 0.f, 0.f, 0.f};
    int cur = 0;
    for (int jt = 0; jt <= ib; ++jt) {
        if (jt < ib)
            stage64(Qp + (size_t)(jt + 1) * 8192, 128, (char*)Ql[cur ^ 1], w, lane);
        float part[4] = {0.f, 0.f, 0.f, 0.f};
#pragma unroll
        for (int nf = 0; nf < 4; ++nf) {
            const int brow = nf * 16 + ln;
            const int bsw  = (brow ^ (brow >> 3)) & 7;
            bf16x8_t b0 = *(const bf16x8_t*)&Ql[cur][brow * 64 + ((g ^ bsw) << 3)];
            bf16x8_t b1 = *(const bf16x8_t*)&Ql[cur][brow * 64 + (((4 + g) ^ bsw) << 3)];
            f32x4_t a = (f32x4_t){0.f, 0.f, 0.f, 0.f};
            a = __builtin_amdgcn_mfma_f32_16x16x32_bf16(ak0, b0, a, 0, 0, 0);
            a = __builtin_amdgcn_mfma_f32_16x16x32_bf16(ak1, b1, a, 0, 0, 0);
            const int j = jt * 64 + nf * 16 + ln;
#pragma unroll
            for (int r = 0; r < 4; ++r)
                part[r] += (j <= irow + r) ? __expf(a[r] * 0.125f) : 0.f;
        }
#pragma unroll
        for (int r = 0; r < 4; ++r) {
            float p = part[r];
            p += __shfl_xor(p, 1);
            p += __shfl_xor(p, 2);
            p += __shfl_xor(p, 4);
            p += __shfl_xor(p, 8);
            lsum[r] += p;
        }
        __syncthreads();
        cur ^= 1;
    }
    if (ln == 0) {
#pragma unroll
        for (int r = 0; r < 4; ++r)
            invS[(size_t)bh * SQ + irow + r] = 1.f / lsum[r];
    }
}

// ---------------------------------------------------------------------------
// K2b (fused): per (bh, j-block of 64):
//   for i-tiles it=jb..15: recompute scores (Q hoisted in regs, K staged),
//   dist = exp(s)*invS[i] -> f32 global write; same values -> bf16 dT (LDS,
//   in-register transpose via 4x ds_write_b64); PV MFMA with pre-transposed
//   V tile (gld_lds staged). Zero-fills the upper-triangle tiles it<jb.
// Replaces old K2-passB + K3: no dist re-read from HBM.
// ---------------------------------------------------------------------------
__global__ __launch_bounds__(256, 2)
void dist_pv_kernel(const bf16* __restrict__ Kh, const bf16* __restrict__ Qh,
                    const bf16* __restrict__ Vt, const float* __restrict__ invS,
                    float* __restrict__ Dist, bf16* __restrict__ att4)
{
    __shared__ alignas(16) bf16 Kl[2][64 * 64];
    __shared__ alignas(16) bf16 Vl[2][64 * 64];
    __shared__ alignas(16) bf16 Ql[64 * 64];
    __shared__ alignas(16) bf16 dT[64 * 72];
    const int tid = threadIdx.x, lane = tid & 63, w = tid >> 6;
    const int g = lane >> 4, ln = lane & 15;
    const int jb = blockIdx.x, bh = blockIdx.y;
    const char* Kp = (const char*)(Kh + (size_t)bh * SQ * DKK);
    const char* Qp = (const char*)(Qh + (size_t)bh * SQ * DKK);
    const char* Vp = (const char*)(Vt + (size_t)bh * DKK * SQ);
    float* Dp = Dist + (size_t)bh * SQ * SQ;
    const float* ivp = invS + (size_t)bh * SQ;

    // hoist Q block (rows j) into register fragments
    stage64(Qp + (size_t)jb * 8192, 128, (char*)Ql, w, lane);
    __syncthreads();
    bf16x8_t bq[4][2];
#pragma unroll
    for (int nf = 0; nf < 4; ++nf) {
        const int brow = nf * 16 + ln;
        const int bsw  = (brow ^ (brow >> 3)) & 7;
        bq[nf][0] = *(const bf16x8_t*)&Ql[brow * 64 + ((g ^ bsw) << 3)];
        bq[nf][1] = *(const bf16x8_t*)&Ql[brow * 64 + (((4 + g) ^ bsw) << 3)];
    }

    // prologue stage of first i-tile; zero-fill hides its latency
    stage64(Kp + (size_t)jb * 8192, 128, (char*)Kl[0], w, lane);
    stage64(Vp + (size_t)jb * 128, 2048, (char*)Vl[0], w, lane);

    const f32x4_t zero4 = (f32x4_t){0.f, 0.f, 0.f, 0.f};
    for (int it0 = 0; it0 < jb; ++it0) {
#pragma unroll
        for (int q = 0; q < 4; ++q) {
            const int cid = q * 256 + tid;
            const int row = cid >> 4, ch = cid & 15;
            *(f32x4_t*)(Dp + (size_t)(it0 * 64 + row) * SQ + jb * 64 + ch * 4) = zero4;
        }
    }
    __syncthreads();

    const int arow = w * 16 + ln;
    const int asw  = (arow ^ (arow >> 3)) & 7;
    f32x4_t accPV[4];
#pragma unroll
    for (int nf = 0; nf < 4; ++nf) accPV[nf] = zero4;

    int cur = 0;
    for (int it = jb; it < 16; ++it) {
        if (it < 15) {   // prefetch next K/V tiles into other buffer
            stage64(Kp + (size_t)(it + 1) * 8192, 128, (char*)Kl[cur ^ 1], w, lane);
            stage64(Vp + (size_t)(it + 1) * 128, 2048, (char*)Vl[cur ^ 1], w, lane);
        }
        const int i0 = it * 64 + w * 16 + g * 4;
        float iv[4];
#pragma unroll
        for (int r = 0; r < 4; ++r) iv[r] = ivp[i0 + r];

        const bf16x8_t ak0 = *(const bf16x8_t*)&Kl[cur][arow * 64 + ((g ^ asw) << 3)];
        const bf16x8_t ak1 = *(const bf16x8_t*)&Kl[cur][arow * 64 + (((4 + g) ^ asw) << 3)];
#pragma unroll
        for (int nf = 0; nf < 4; ++nf) {
            f32x4_t a = zero4;
            a = __builtin_amdgcn_mfma_f32_16x16x32_bf16(ak0, bq[nf][0], a, 0, 0, 0);
            a = __builtin_amdgcn_mfma_f32_16x16x32_bf16(ak1, bq[nf][1], a, 0, 0, 0);
            const int jl = nf * 16 + ln;
            const int j  = jb * 64 + jl;
            bf16x4_t pk;
#pragma unroll
            for (int r = 0; r < 4; ++r) {
                const float e = (j <= i0 + r) ? __expf(a[r] * 0.125f) * iv[r] : 0.f;
                Dp[(size_t)(i0 + r) * SQ + j] = e;
                pk[r] = (__bf16)e;
            }
            // transpose into dT[j][i] (pad 72 + xor swizzle), 4 bf16 per b64 write
            *(bf16x4_t*)&dT[jl * 72 + ((w * 16 + g * 4) ^ (((jl >> 3) & 7) << 3))] = pk;
        }
        __syncthreads();   // dT visible; prefetched tiles drained
#pragma unroll
        for (int kk = 0; kk < 2; ++kk) {
            const int abase = (kk * 32 + g * 8) ^ (((arow >> 3) & 7) << 3);
            const bf16x8_t a = *(const bf16x8_t*)&dT[arow * 72 + abase];
#pragma unroll
            for (int nf = 0; nf < 4; ++nf) {
                const int brow = nf * 16 + ln;
                const int bsw  = (brow ^ (brow >> 3)) & 7;
                const bf16x8_t b =
                    *(const bf16x8_t*)&Vl[cur][brow * 64 + (((kk * 4 + g) ^ bsw) << 3)];
                accPV[nf] = __builtin_amdgcn_mfma_f32_16x16x32_bf16(a, b, accPV[nf], 0, 0, 0);
            }
        }
        __syncthreads();   // protect dT + K/V buffers before next iteration
        cur ^= 1;
    }

    const int h = bh >> 3, b = bh & 7;
#pragma unroll
    for (int nf = 0; nf < 4; ++nf) {
#pragma unroll
        for (int r = 0; r < 4; ++r) {
            const int j = jb * 64 + w * 16 + g * 4 + r;
            att4[(size_t)(j * 8 + b) * HD + h * 64 + nf * 16 + ln] =
                __float2bfloat16(accPV[nf][r]);
        }
    }
}

// ---------------------------------------------------------------------------
extern "C" void kernel_launch(void* const* d_in, const int* in_sizes, int n_in,
                              void* d_out, int out_size, void* d_ws, size_t ws_size,
                              hipStream_t stream)
{
    const float* value = (const float*)d_in[0];
    const float* key_  = (const float*)d_in[1];
    const float* query = (const float*)d_in[2];
    const float* Wq    = (const float*)d_in[3];
    const float* Wk    = (const float*)d_in[4];
    const float* Wv    = (const float*)d_in[5];
    const float* Wo    = (const float*)d_in[6];

    float* out  = (float*)d_out;                       // (S,B,H) f32
    float* dist = out + (size_t)SQ * NB * HD;          // (128,1024,1024) f32
    float* invS = out;   // scratch: 512 KB in out region, overwritten by K4

    char* ws   = (char*)d_ws;
    bf16* Qh   = (bf16*)(ws);                          // 16 MB each
    bf16* Kh   = (bf16*)(ws + (size_t)16 * 1024 * 1024);
    bf16* Vt   = (bf16*)(ws + (size_t)32 * 1024 * 1024);   // V transposed [bh][d][s]
    bf16* att4 = (bf16*)(ws + (size_t)48 * 1024 * 1024);

    dim3 blk(256);
    // K1: projections (f32 in) -> head-major bf16 Qh/Kh + transposed Vt
    gemm_kernel<<<dim3(8, 64, 3), blk, 0, stream>>>(
        query, key_, value, Wq, Wk, Wv, Qh, Kh, Vt, 0);
    // K2a: softmax denominators -> invS (stashed in out, consumed before K4)
    rowsum_kernel<<<dim3(16, 128), blk, 0, stream>>>(Kh, Qh, invS);
    // K2b: fused dist write (output 2) + PV -> bf16 att4
    dist_pv_kernel<<<dim3(16, 128), blk, 0, stream>>>(Kh, Qh, Vt, invS, dist, att4);
    // K4: out = att4 @ Wo^T -> f32 d_out (output 1)
    gemm_kernel<<<dim3(8, 64, 1), blk, 0, stream>>>(
        att4, att4, att4, Wo, Wo, Wo, out, out, out, 1);
}

// Round 2
// 940.801 us; speedup vs baseline: 1.0701x; 1.0127x over previous
//
#include <hip/hip_runtime.h>
#include <hip/hip_bf16.h>
#include <stdint.h>

#define SQ   1024
#define NB   8
#define HD   1024
#define NHD  16
#define DKK  64
// bh = NHD*NB = 128

typedef __bf16 bf16x8_t __attribute__((ext_vector_type(8)));
typedef __bf16 bf16x4_t __attribute__((ext_vector_type(4)));
typedef float  f32x4_t  __attribute__((ext_vector_type(4)));
typedef __hip_bfloat16 bf16;

__device__ __forceinline__ void gld_lds16(const void* g, void* l) {
    __builtin_amdgcn_global_load_lds(
        (__attribute__((address_space(1))) void*)const_cast<void*>(g),
        (__attribute__((address_space(3))) void*)l,
        16, 0, 0);
}

__device__ __forceinline__ bf16x8_t cvt8(float4 a, float4 b) {
    bf16x8_t r;
    r[0] = (__bf16)a.x; r[1] = (__bf16)a.y; r[2] = (__bf16)a.z; r[3] = (__bf16)a.w;
    r[4] = (__bf16)b.x; r[5] = (__bf16)b.y; r[6] = (__bf16)b.z; r[7] = (__bf16)b.w;
    return r;
}

// stage a 64x64 bf16 tile (64 rows x 128B) into LDS via global_load_lds,
// bank-swizzled on the SOURCE side (LDS stays linear).
__device__ __forceinline__ void stage64(const char* gbase, int rowstride,
                                        char* lbase, int w, int lane) {
#pragma unroll
    for (int q = 0; q < 2; ++q) {
        const int cid = (q * 4 + w) * 64 + lane;
        const int r   = cid >> 3;
        const int cc  = (cid & 7) ^ ((r ^ (r >> 3)) & 7);
        gld_lds16(gbase + r * rowstride + cc * 16, lbase + cid * 16);
    }
}

// ---------------------------------------------------------------------------
// GEMM: C[m,o] = sum_k A[m,k] * W[o,k]   (A: 8192x1024, W: 1024x1024)
// W always f32 (cvt-staged). mode 0: A f32, Out bf16 scatter:
//   z<2 : head-major  Out[((h*8+b)*SQ + s)*64 + d]
//   z==2: V transposed Out[((h*8+b)*64 + d)*SQ + s]
// mode 1: A bf16 (global_load_lds), Out = f32 row-major Out[m*HD + o]
// Double-buffered LDS, issue-loads-early / compute / commit / one barrier.
// ---------------------------------------------------------------------------
__global__ __launch_bounds__(256, 2)
void gemm_kernel(const void* __restrict__ A0, const void* __restrict__ A1,
                 const void* __restrict__ A2,
                 const float* __restrict__ W0, const float* __restrict__ W1,
                 const float* __restrict__ W2,
                 void* __restrict__ O0, void* __restrict__ O1,
                 void* __restrict__ O2, int mode)
{
    const int z = blockIdx.z;
    const void*  A  = (z == 0) ? A0 : (z == 1) ? A1 : A2;
    const float* Wf = (z == 0) ? W0 : (z == 1) ? W1 : W2;
    void*        Ov = (z == 0) ? O0 : (z == 1) ? O1 : O2;

    __shared__ alignas(16) bf16 lA[2][128 * 32];
    __shared__ alignas(16) bf16 lB[2][128 * 32];

    const int tid  = threadIdx.x;
    const int lane = tid & 63;
    const int w    = tid >> 6;
    const int wr   = w >> 1;
    const int wc   = w & 1;
    const int g    = lane >> 4;
    const int ln   = lane & 15;
    const int bm   = blockIdx.y;
    const int bn   = blockIdx.x;

    f32x4_t acc[4][4];
#pragma unroll
    for (int i = 0; i < 4; ++i)
#pragma unroll
        for (int j = 0; j < 4; ++j)
            acc[i][j] = (f32x4_t){0.f, 0.f, 0.f, 0.f};

    const size_t arow0 = (size_t)bm * 128;
    const size_t brow0 = (size_t)bn * 128;
    const float* Af = (const float*)A;
    const bf16*  Ab = (const bf16*)A;

    int scid[2], srow[2], sch[2];
#pragma unroll
    for (int q = 0; q < 2; ++q) {
        const int cid = (q * 4 + w) * 64 + lane;
        scid[q] = cid;
        srow[q] = cid >> 2;
        sch[q]  = (cid & 3) ^ ((srow[q] ^ (srow[q] >> 2)) & 3);   // bank swizzle
    }

    float4 pa[4], pw[4];

    auto issue_loads = [&](int k0, int buf) {
#pragma unroll
        for (int q = 0; q < 2; ++q) {
            const float4* wsrc = (const float4*)(Wf + (brow0 + srow[q]) * HD + k0 + sch[q] * 8);
            pw[q * 2]     = wsrc[0];
            pw[q * 2 + 1] = wsrc[1];
        }
        if (mode == 0) {
#pragma unroll
            for (int q = 0; q < 2; ++q) {
                const float4* asrc = (const float4*)(Af + (arow0 + srow[q]) * HD + k0 + sch[q] * 8);
                pa[q * 2]     = asrc[0];
                pa[q * 2 + 1] = asrc[1];
            }
        } else {
#pragma unroll
            for (int q = 0; q < 2; ++q)
                gld_lds16((const char*)Ab + ((arow0 + srow[q]) * HD + k0) * 2 + sch[q] * 16,
                          (char*)&lA[buf][0] + scid[q] * 16);
        }
    };
    auto commit_writes = [&](int buf) {
#pragma unroll
        for (int q = 0; q < 2; ++q)
            *(bf16x8_t*)&lB[buf][scid[q] * 8] = cvt8(pw[q * 2], pw[q * 2 + 1]);
        if (mode == 0) {
#pragma unroll
            for (int q = 0; q < 2; ++q)
                *(bf16x8_t*)&lA[buf][scid[q] * 8] = cvt8(pa[q * 2], pa[q * 2 + 1]);
        }
    };

    issue_loads(0, 0);
    commit_writes(0);
    __syncthreads();

    int cur = 0;
    for (int ks = 0; ks < 32; ++ks) {
        if (ks < 31) issue_loads((ks + 1) * 32, cur ^ 1);   // prefetch next tile
        bf16x8_t av[4], bv[4];
#pragma unroll
        for (int mi = 0; mi < 4; ++mi) {
            const int row = wr * 64 + mi * 16 + ln;
            av[mi] = *(const bf16x8_t*)&lA[cur][row * 32 + ((g ^ ((row ^ (row >> 2)) & 3)) << 3)];
        }
#pragma unroll
        for (int ni = 0; ni < 4; ++ni) {
            const int row = wc * 64 + ni * 16 + ln;
            bv[ni] = *(const bf16x8_t*)&lB[cur][row * 32 + ((g ^ ((row ^ (row >> 2)) & 3)) << 3)];
        }
#pragma unroll
        for (int mi = 0; mi < 4; ++mi)
#pragma unroll
            for (int ni = 0; ni < 4; ++ni)
                acc[mi][ni] = __builtin_amdgcn_mfma_f32_16x16x32_bf16(
                    av[mi], bv[ni], acc[mi][ni], 0, 0, 0);
        if (ks < 31) commit_writes(cur ^ 1);                // loads had MFMA phase to land
        __syncthreads();
        cur ^= 1;
    }

    bf16*  Ob = (bf16*)Ov;
    float* Of = (float*)Ov;
#pragma unroll
    for (int mi = 0; mi < 4; ++mi) {
#pragma unroll
        for (int ni = 0; ni < 4; ++ni) {
            const int o = bn * 128 + wc * 64 + ni * 16 + ln;
#pragma unroll
            for (int r = 0; r < 4; ++r) {
                const int m = bm * 128 + wr * 64 + mi * 16 + g * 4 + r;
                const float v = acc[mi][ni][r];
                if (mode == 0) {
                    const int h = o >> 6, d = o & 63;
                    const int s = m >> 3, b = m & 7;
                    if (z == 2)
                        Ob[((size_t)((h * 8 + b) * DKK + d)) * SQ + s] = __float2bfloat16(v);
                    else
                        Ob[(((size_t)(h * 8 + b) * SQ + s) << 6) + d] = __float2bfloat16(v);
                } else {
                    Of[(size_t)m * HD + o] = v;
                }
            }
        }
    }
}

// ---------------------------------------------------------------------------
// K2a: per (bh, i-block of 64): rowsum of exp(K.Q^T/8) over unmasked j,
// writes invS[bh][i] = 1/rowsum. (No max subtraction: |s| <~ 3.)
// K frags hoisted to regs; Q double-buffered, 1 barrier/tile.
// Shuffle reduction DEFERRED to a single pass at the end (associativity).
// ---------------------------------------------------------------------------
__global__ __launch_bounds__(256, 2)
void rowsum_kernel(const bf16* __restrict__ Kh, const bf16* __restrict__ Qh,
                   float* __restrict__ invS)
{
    __shared__ alignas(16) bf16 Kl[64 * 64];
    __shared__ alignas(16) bf16 Ql[2][64 * 64];
    const int tid = threadIdx.x, lane = tid & 63, w = tid >> 6;
    const int g = lane >> 4, ln = lane & 15;
    const int ib = 15 - (int)blockIdx.x, bh = blockIdx.y;   // heavy blocks first
    const char* Kp = (const char*)(Kh + ((size_t)bh * SQ + ib * 64) * DKK);
    const char* Qp = (const char*)(Qh + (size_t)bh * SQ * DKK);

    stage64(Kp, 128, (char*)Kl, w, lane);
    stage64(Qp, 128, (char*)Ql[0], w, lane);
    __syncthreads();

    const int arow = w * 16 + ln;
    const int asw  = (arow ^ (arow >> 3)) & 7;
    const bf16x8_t ak0 = *(const bf16x8_t*)&Kl[arow * 64 + ((g ^ asw) << 3)];
    const bf16x8_t ak1 = *(const bf16x8_t*)&Kl[arow * 64 + (((4 + g) ^ asw) << 3)];
    const int irow = ib * 64 + w * 16 + g * 4;

    float lsum[4] = {0.f, 0.f, 0.f, 0.f};   // per-lane partials, reduce ONCE at end
    int cur = 0;
    for (int jt = 0; jt <= ib; ++jt) {
        if (jt < ib)
            stage64(Qp + (size_t)(jt + 1) * 8192, 128, (char*)Ql[cur ^ 1], w, lane);
#pragma unroll
        for (int nf = 0; nf < 4; ++nf) {
            const int brow = nf * 16 + ln;
            const int bsw  = (brow ^ (brow >> 3)) & 7;
            bf16x8_t b0 = *(const bf16x8_t*)&Ql[cur][brow * 64 + ((g ^ bsw) << 3)];
            bf16x8_t b1 = *(const bf16x8_t*)&Ql[cur][brow * 64 + (((4 + g) ^ bsw) << 3)];
            f32x4_t a = (f32x4_t){0.f, 0.f, 0.f, 0.f};
            __builtin_amdgcn_s_setprio(1);
            a = __builtin_amdgcn_mfma_f32_16x16x32_bf16(ak0, b0, a, 0, 0, 0);
            a = __builtin_amdgcn_mfma_f32_16x16x32_bf16(ak1, b1, a, 0, 0, 0);
            __builtin_amdgcn_s_setprio(0);
            const int j = jt * 64 + nf * 16 + ln;
#pragma unroll
            for (int r = 0; r < 4; ++r)
                lsum[r] += (j <= irow + r) ? __expf(a[r] * 0.125f) : 0.f;
        }
        __syncthreads();
        cur ^= 1;
    }
#pragma unroll
    for (int r = 0; r < 4; ++r) {
        float p = lsum[r];
        p += __shfl_xor(p, 1);
        p += __shfl_xor(p, 2);
        p += __shfl_xor(p, 4);
        p += __shfl_xor(p, 8);
        lsum[r] = p;
    }
    if (ln == 0) {
#pragma unroll
        for (int r = 0; r < 4; ++r)
            invS[(size_t)bh * SQ + irow + r] = 1.f / lsum[r];
    }
}

// ---------------------------------------------------------------------------
// K2b (fused): per (bh, j-block of 64):
//   for i-tiles it=jb..15: recompute scores (Q hoisted in regs, K staged),
//   dist = exp(s)*invS[i]; values staged f32 in dF (LDS) + bf16 in dT
//   (transposed); after barrier: vectorized dwordx4 dist flush (overlapped
//   with PV MFMAs using pre-transposed V). Zero-fills tiles it<jb.
// ---------------------------------------------------------------------------
__global__ __launch_bounds__(256, 2)
void dist_pv_kernel(const bf16* __restrict__ Kh, const bf16* __restrict__ Qh,
                    const bf16* __restrict__ Vt, const float* __restrict__ invS,
                    float* __restrict__ Dist, bf16* __restrict__ att4)
{
    __shared__ alignas(16) bf16 Kl[2][64 * 64];
    __shared__ alignas(16) bf16 Vl[2][64 * 64];
    __shared__ alignas(16) bf16 Ql[64 * 64];
    __shared__ alignas(16) bf16 dT[64 * 72];
    __shared__ alignas(16) float dF[64 * 68];   // f32 staging for vectorized store
    const int tid = threadIdx.x, lane = tid & 63, w = tid >> 6;
    const int g = lane >> 4, ln = lane & 15;
    const int jb = blockIdx.x, bh = blockIdx.y;
    const char* Kp = (const char*)(Kh + (size_t)bh * SQ * DKK);
    const char* Qp = (const char*)(Qh + (size_t)bh * SQ * DKK);
    const char* Vp = (const char*)(Vt + (size_t)bh * DKK * SQ);
    float* Dp = Dist + (size_t)bh * SQ * SQ;
    const float* ivp = invS + (size_t)bh * SQ;

    // hoist Q block (rows j) into register fragments
    stage64(Qp + (size_t)jb * 8192, 128, (char*)Ql, w, lane);
    __syncthreads();
    bf16x8_t bq[4][2];
#pragma unroll
    for (int nf = 0; nf < 4; ++nf) {
        const int brow = nf * 16 + ln;
        const int bsw  = (brow ^ (brow >> 3)) & 7;
        bq[nf][0] = *(const bf16x8_t*)&Ql[brow * 64 + ((g ^ bsw) << 3)];
        bq[nf][1] = *(const bf16x8_t*)&Ql[brow * 64 + (((4 + g) ^ bsw) << 3)];
    }

    // prologue stage of first i-tile; zero-fill hides its latency
    stage64(Kp + (size_t)jb * 8192, 128, (char*)Kl[0], w, lane);
    stage64(Vp + (size_t)jb * 128, 2048, (char*)Vl[0], w, lane);

    const f32x4_t zero4 = (f32x4_t){0.f, 0.f, 0.f, 0.f};
    for (int it0 = 0; it0 < jb; ++it0) {
#pragma unroll
        for (int q = 0; q < 4; ++q) {
            const int cid = q * 256 + tid;
            const int row = cid >> 4, ch = cid & 15;
            *(f32x4_t*)(Dp + (size_t)(it0 * 64 + row) * SQ + jb * 64 + ch * 4) = zero4;
        }
    }
    __syncthreads();

    const int arow = w * 16 + ln;
    const int asw  = (arow ^ (arow >> 3)) & 7;
    f32x4_t accPV[4];
#pragma unroll
    for (int nf = 0; nf < 4; ++nf) accPV[nf] = zero4;

    int cur = 0;
    for (int it = jb; it < 16; ++it) {
        if (it < 15) {   // prefetch next K/V tiles into other buffer
            stage64(Kp + (size_t)(it + 1) * 8192, 128, (char*)Kl[cur ^ 1], w, lane);
            stage64(Vp + (size_t)(it + 1) * 128, 2048, (char*)Vl[cur ^ 1], w, lane);
        }
        const int i0 = it * 64 + w * 16 + g * 4;
        float iv[4];
#pragma unroll
        for (int r = 0; r < 4; ++r) iv[r] = ivp[i0 + r];

        const bf16x8_t ak0 = *(const bf16x8_t*)&Kl[cur][arow * 64 + ((g ^ asw) << 3)];
        const bf16x8_t ak1 = *(const bf16x8_t*)&Kl[cur][arow * 64 + (((4 + g) ^ asw) << 3)];
#pragma unroll
        for (int nf = 0; nf < 4; ++nf) {
            f32x4_t a = zero4;
            __builtin_amdgcn_s_setprio(1);
            a = __builtin_amdgcn_mfma_f32_16x16x32_bf16(ak0, bq[nf][0], a, 0, 0, 0);
            a = __builtin_amdgcn_mfma_f32_16x16x32_bf16(ak1, bq[nf][1], a, 0, 0, 0);
            __builtin_amdgcn_s_setprio(0);
            const int jl = nf * 16 + ln;
            const int j  = jb * 64 + jl;
            bf16x4_t pk;
#pragma unroll
            for (int r = 0; r < 4; ++r) {
                const float e = (j <= i0 + r) ? __expf(a[r] * 0.125f) * iv[r] : 0.f;
                dF[(w * 16 + g * 4 + r) * 68 + jl] = e;       // f32 stage (2-way max)
                pk[r] = (__bf16)e;
            }
            // transpose into dT[j][i] (pad 72 + xor swizzle), 4 bf16 per b64 write
            *(bf16x4_t*)&dT[jl * 72 + ((w * 16 + g * 4) ^ (((jl >> 3) & 7) << 3))] = pk;
        }
        __syncthreads();   // dT/dF visible; prefetched tiles drained

        // vectorized dist flush: 16B/lane, 256B contiguous segments; stores
        // retire under the PV MFMA cluster before the next barrier.
#pragma unroll
        for (int q = 0; q < 4; ++q) {
            const int cid = q * 256 + tid;
            const int row = cid >> 4;
            const int jc  = (cid & 15) << 2;
            const f32x4_t fv = *(const f32x4_t*)&dF[row * 68 + jc];
            *(f32x4_t*)(Dp + (size_t)(it * 64 + row) * SQ + jb * 64 + jc) = fv;
        }
#pragma unroll
        for (int kk = 0; kk < 2; ++kk) {
            const int abase = (kk * 32 + g * 8) ^ (((arow >> 3) & 7) << 3);
            const bf16x8_t a = *(const bf16x8_t*)&dT[arow * 72 + abase];
            __builtin_amdgcn_s_setprio(1);
#pragma unroll
            for (int nf = 0; nf < 4; ++nf) {
                const int brow = nf * 16 + ln;
                const int bsw  = (brow ^ (brow >> 3)) & 7;
                const bf16x8_t b =
                    *(const bf16x8_t*)&Vl[cur][brow * 64 + (((kk * 4 + g) ^ bsw) << 3)];
                accPV[nf] = __builtin_amdgcn_mfma_f32_16x16x32_bf16(a, b, accPV[nf], 0, 0, 0);
            }
            __builtin_amdgcn_s_setprio(0);
        }
        __syncthreads();   // protect dT/dF + K/V buffers before next iteration
        cur ^= 1;
    }

    const int h = bh >> 3, b = bh & 7;
#pragma unroll
    for (int nf = 0; nf < 4; ++nf) {
#pragma unroll
        for (int r = 0; r < 4; ++r) {
            const int j = jb * 64 + w * 16 + g * 4 + r;
            att4[(size_t)(j * 8 + b) * HD + h * 64 + nf * 16 + ln] =
                __float2bfloat16(accPV[nf][r]);
        }
    }
}

// ---------------------------------------------------------------------------
extern "C" void kernel_launch(void* const* d_in, const int* in_sizes, int n_in,
                              void* d_out, int out_size, void* d_ws, size_t ws_size,
                              hipStream_t stream)
{
    const float* value = (const float*)d_in[0];
    const float* key_  = (const float*)d_in[1];
    const float* query = (const float*)d_in[2];
    const float* Wq    = (const float*)d_in[3];
    const float* Wk    = (const float*)d_in[4];
    const float* Wv    = (const float*)d_in[5];
    const float* Wo    = (const float*)d_in[6];

    float* out  = (float*)d_out;                       // (S,B,H) f32
    float* dist = out + (size_t)SQ * NB * HD;          // (128,1024,1024) f32
    float* invS = out;   // scratch: 512 KB in out region, overwritten by K4

    char* ws   = (char*)d_ws;
    bf16* Qh   = (bf16*)(ws);                          // 16 MB each
    bf16* Kh   = (bf16*)(ws + (size_t)16 * 1024 * 1024);
    bf16* Vt   = (bf16*)(ws + (size_t)32 * 1024 * 1024);   // V transposed [bh][d][s]
    bf16* att4 = (bf16*)(ws + (size_t)48 * 1024 * 1024);

    dim3 blk(256);
    // K1: projections (f32 in) -> head-major bf16 Qh/Kh + transposed Vt
    gemm_kernel<<<dim3(8, 64, 3), blk, 0, stream>>>(
        query, key_, value, Wq, Wk, Wv, Qh, Kh, Vt, 0);
    // K2a: softmax denominators -> invS (stashed in out, consumed before K4)
    rowsum_kernel<<<dim3(16, 128), blk, 0, stream>>>(Kh, Qh, invS);
    // K2b: fused dist write (output 2) + PV -> bf16 att4
    dist_pv_kernel<<<dim3(16, 128), blk, 0, stream>>>(Kh, Qh, Vt, invS, dist, att4);
    // K4: out = att4 @ Wo^T -> f32 d_out (output 1)
    gemm_kernel<<<dim3(8, 64, 1), blk, 0, stream>>>(
        att4, att4, att4, Wo, Wo, Wo, out, out, out, 1);
}

// Round 4
// 902.960 us; speedup vs baseline: 1.1150x; 1.0419x over previous
//
#include <hip/hip_runtime.h>
#include <hip/hip_bf16.h>
#include <stdint.h>

#define SQ   1024
#define NB   8
#define HD   1024
#define NHD  16
#define DKK  64
// bh = NHD*NB = 128

typedef __bf16 bf16x8_t __attribute__((ext_vector_type(8)));
typedef __bf16 bf16x4_t __attribute__((ext_vector_type(4)));
typedef float  f32x4_t  __attribute__((ext_vector_type(4)));
typedef __hip_bfloat16 bf16;

#define SB0() __builtin_amdgcn_sched_barrier(0)

__device__ __forceinline__ void gld_lds16(const void* g, void* l) {
    __builtin_amdgcn_global_load_lds(
        (__attribute__((address_space(1))) void*)const_cast<void*>(g),
        (__attribute__((address_space(3))) void*)l,
        16, 0, 0);
}

// raw barrier, full vmem+lds drain
__device__ __forceinline__ void vm_bar() {
    SB0();
    asm volatile("s_waitcnt vmcnt(0) lgkmcnt(0)" ::: "memory");
    __builtin_amdgcn_s_barrier();
    SB0();
}
// raw barrier, LDS-only drain (vmem prefetch/stores stay in flight)
__device__ __forceinline__ void lgkm_bar() {
    SB0();
    asm volatile("s_waitcnt lgkmcnt(0)" ::: "memory");
    __builtin_amdgcn_s_barrier();
    SB0();
}

__device__ __forceinline__ bf16x8_t cvt8(float4 a, float4 b) {
    bf16x8_t r;
    r[0] = (__bf16)a.x; r[1] = (__bf16)a.y; r[2] = (__bf16)a.z; r[3] = (__bf16)a.w;
    r[4] = (__bf16)b.x; r[5] = (__bf16)b.y; r[6] = (__bf16)b.z; r[7] = (__bf16)b.w;
    return r;
}

// stage a 64x64 bf16 tile (64 rows x 128B) into LDS, source-side swizzle
__device__ __forceinline__ void stage64(const char* gbase, int rowstride,
                                        char* lbase, int w, int lane) {
#pragma unroll
    for (int q = 0; q < 2; ++q) {
        const int cid = (q * 4 + w) * 64 + lane;
        const int r   = cid >> 3;
        const int cc  = (cid & 7) ^ ((r ^ (r >> 3)) & 7);
        gld_lds16(gbase + r * rowstride + cc * 16, lbase + cid * 16);
    }
}

// stage a 128x32 bf16 tile (128 rows x 64B, row stride HD*2B), source swizzle
__device__ __forceinline__ void stage_g(const char* gbase, char* lbase,
                                        int w, int lane) {
#pragma unroll
    for (int q = 0; q < 2; ++q) {
        const int cid = (q * 4 + w) * 64 + lane;
        const int r   = cid >> 2;
        const int ch  = (cid & 3) ^ ((r ^ (r >> 2)) & 3);
        gld_lds16(gbase + r * (HD * 2) + ch * 16, lbase + cid * 16);
    }
}

// ---------------------------------------------------------------------------
// K0: f32 -> bf16 pre-convert (exact partition, 8 elts/thread)
// ---------------------------------------------------------------------------
__global__ __launch_bounds__(256)
void cvt_kernel(const float* __restrict__ s0, const float* __restrict__ s1,
                const float* __restrict__ s2,
                bf16* __restrict__ d0, bf16* __restrict__ d1,
                bf16* __restrict__ d2)
{
    const int z = blockIdx.z;
    const float* s = (z == 0) ? s0 : (z == 1) ? s1 : s2;
    bf16*        d = (z == 0) ? d0 : (z == 1) ? d1 : d2;
    const size_t i = ((size_t)blockIdx.x * 256 + threadIdx.x) * 8;
    const float4 a = *(const float4*)(s + i);
    const float4 b = *(const float4*)(s + i + 4);
    *(bf16x8_t*)(d + i) = cvt8(a, b);
}

// ---------------------------------------------------------------------------
// K1 GEMM (all-bf16): C[m,o] = sum_k A[m,k] * W[o,k]
// Both operands via global_load_lds; TRIPLE-buffered, counted vmcnt(4):
// stage(ks+2) issued after the raw barrier, waited 2 K-steps later.
// Out bf16 scatter: z<2 head-major, z==2 V-transposed [bh][d][s].
// ---------------------------------------------------------------------------
__global__ __launch_bounds__(256, 3)
void gemm_bb(const bf16* __restrict__ A0, const bf16* __restrict__ A1,
             const bf16* __restrict__ A2,
             const bf16* __restrict__ B0, const bf16* __restrict__ B1,
             const bf16* __restrict__ B2,
             bf16* __restrict__ O0, bf16* __restrict__ O1,
             bf16* __restrict__ O2)
{
    const int z = blockIdx.z;
    const bf16* A  = (z == 0) ? A0 : (z == 1) ? A1 : A2;
    const bf16* Bw = (z == 0) ? B0 : (z == 1) ? B1 : B2;
    bf16*       Ob = (z == 0) ? O0 : (z == 1) ? O1 : O2;

    __shared__ alignas(16) bf16 lA[3][128 * 32];
    __shared__ alignas(16) bf16 lB[3][128 * 32];

    const int tid  = threadIdx.x;
    const int lane = tid & 63;
    const int w    = tid >> 6;
    const int wr   = w >> 1;
    const int wc   = w & 1;
    const int g    = lane >> 4;
    const int ln   = lane & 15;
    const int bm   = blockIdx.y;
    const int bn   = blockIdx.x;

    f32x4_t acc[4][4];
#pragma unroll
    for (int i = 0; i < 4; ++i)
#pragma unroll
        for (int j = 0; j < 4; ++j)
            acc[i][j] = (f32x4_t){0.f, 0.f, 0.f, 0.f};

    const char* Ap = (const char*)(A  + (size_t)bm * 128 * HD);
    const char* Bp = (const char*)(Bw + (size_t)bn * 128 * HD);

    auto stg = [&](int ks, int buf) {
        stage_g(Ap + ks * 64, (char*)&lA[buf][0], w, lane);
        stage_g(Bp + ks * 64, (char*)&lB[buf][0], w, lane);
    };

    stg(0, 0);
    stg(1, 1);          // 8 gld_lds outstanding

    for (int ks = 0; ks < 32; ++ks) {
        const int buf = ks % 3;
        SB0();
        if (ks < 31) asm volatile("s_waitcnt vmcnt(4)" ::: "memory");
        else         asm volatile("s_waitcnt vmcnt(0)" ::: "memory");
        __builtin_amdgcn_s_barrier();
        SB0();
        if (ks < 30) stg(ks + 2, (ks + 2) % 3);   // lands 2 K-steps from now

        bf16x8_t av[4], bv[4];
#pragma unroll
        for (int mi = 0; mi < 4; ++mi) {
            const int row = wr * 64 + mi * 16 + ln;
            av[mi] = *(const bf16x8_t*)&lA[buf][row * 32 + ((g ^ ((row ^ (row >> 2)) & 3)) << 3)];
        }
#pragma unroll
        for (int ni = 0; ni < 4; ++ni) {
            const int row = wc * 64 + ni * 16 + ln;
            bv[ni] = *(const bf16x8_t*)&lB[buf][row * 32 + ((g ^ ((row ^ (row >> 2)) & 3)) << 3)];
        }
        __builtin_amdgcn_s_setprio(1);
#pragma unroll
        for (int mi = 0; mi < 4; ++mi)
#pragma unroll
            for (int ni = 0; ni < 4; ++ni)
                acc[mi][ni] = __builtin_amdgcn_mfma_f32_16x16x32_bf16(
                    av[mi], bv[ni], acc[mi][ni], 0, 0, 0);
        __builtin_amdgcn_s_setprio(0);
    }

#pragma unroll
    for (int mi = 0; mi < 4; ++mi) {
#pragma unroll
        for (int ni = 0; ni < 4; ++ni) {
            const int o = bn * 128 + wc * 64 + ni * 16 + ln;
#pragma unroll
            for (int r = 0; r < 4; ++r) {
                const int m = bm * 128 + wr * 64 + mi * 16 + g * 4 + r;
                const float v = acc[mi][ni][r];
                const int h = o >> 6, d = o & 63;
                const int s = m >> 3, b = m & 7;
                if (z == 2)
                    Ob[((size_t)((h * 8 + b) * DKK + d)) * SQ + s] = __float2bfloat16(v);
                else
                    Ob[(((size_t)(h * 8 + b) * SQ + s) << 6) + d] = __float2bfloat16(v);
            }
        }
    }
}

// ---------------------------------------------------------------------------
// K4 GEMM (Round-2 proven structure): out[m,o] = sum_k att4[m,k] * Wo[o,k]
// A bf16 via global_load_lds; Wo f32 register-staged cvt; dbuf + syncthreads.
// ---------------------------------------------------------------------------
__global__ __launch_bounds__(256, 2)
void gemm_k4(const bf16* __restrict__ A, const float* __restrict__ Wf,
             float* __restrict__ Of)
{
    __shared__ alignas(16) bf16 lA[2][128 * 32];
    __shared__ alignas(16) bf16 lB[2][128 * 32];

    const int tid  = threadIdx.x;
    const int lane = tid & 63;
    const int w    = tid >> 6;
    const int wr   = w >> 1;
    const int wc   = w & 1;
    const int g    = lane >> 4;
    const int ln   = lane & 15;
    const int bm   = blockIdx.y;
    const int bn   = blockIdx.x;

    f32x4_t acc[4][4];
#pragma unroll
    for (int i = 0; i < 4; ++i)
#pragma unroll
        for (int j = 0; j < 4; ++j)
            acc[i][j] = (f32x4_t){0.f, 0.f, 0.f, 0.f};

    const size_t arow0 = (size_t)bm * 128;
    const size_t brow0 = (size_t)bn * 128;

    int scid[2], srow[2], sch[2];
#pragma unroll
    for (int q = 0; q < 2; ++q) {
        const int cid = (q * 4 + w) * 64 + lane;
        scid[q] = cid;
        srow[q] = cid >> 2;
        sch[q]  = (cid & 3) ^ ((srow[q] ^ (srow[q] >> 2)) & 3);
    }

    float4 pw[4];

    auto issue_loads = [&](int k0, int buf) {
#pragma unroll
        for (int q = 0; q < 2; ++q) {
            const float4* wsrc = (const float4*)(Wf + (brow0 + srow[q]) * HD + k0 + sch[q] * 8);
            pw[q * 2]     = wsrc[0];
            pw[q * 2 + 1] = wsrc[1];
        }
#pragma unroll
        for (int q = 0; q < 2; ++q)
            gld_lds16((const char*)A + ((arow0 + srow[q]) * HD + k0) * 2 + sch[q] * 16,
                      (char*)&lA[buf][0] + scid[q] * 16);
    };
    auto commit_writes = [&](int buf) {
#pragma unroll
        for (int q = 0; q < 2; ++q)
            *(bf16x8_t*)&lB[buf][scid[q] * 8] = cvt8(pw[q * 2], pw[q * 2 + 1]);
    };

    issue_loads(0, 0);
    commit_writes(0);
    __syncthreads();

    int cur = 0;
    for (int ks = 0; ks < 32; ++ks) {
        if (ks < 31) issue_loads((ks + 1) * 32, cur ^ 1);
        bf16x8_t av[4], bv[4];
#pragma unroll
        for (int mi = 0; mi < 4; ++mi) {
            const int row = wr * 64 + mi * 16 + ln;
            av[mi] = *(const bf16x8_t*)&lA[cur][row * 32 + ((g ^ ((row ^ (row >> 2)) & 3)) << 3)];
        }
#pragma unroll
        for (int ni = 0; ni < 4; ++ni) {
            const int row = wc * 64 + ni * 16 + ln;
            bv[ni] = *(const bf16x8_t*)&lB[cur][row * 32 + ((g ^ ((row ^ (row >> 2)) & 3)) << 3)];
        }
#pragma unroll
        for (int mi = 0; mi < 4; ++mi)
#pragma unroll
            for (int ni = 0; ni < 4; ++ni)
                acc[mi][ni] = __builtin_amdgcn_mfma_f32_16x16x32_bf16(
                    av[mi], bv[ni], acc[mi][ni], 0, 0, 0);
        if (ks < 31) commit_writes(cur ^ 1);
        __syncthreads();
        cur ^= 1;
    }

#pragma unroll
    for (int mi = 0; mi < 4; ++mi) {
#pragma unroll
        for (int ni = 0; ni < 4; ++ni) {
            const int o = bn * 128 + wc * 64 + ni * 16 + ln;
#pragma unroll
            for (int r = 0; r < 4; ++r) {
                const int m = bm * 128 + wr * 64 + mi * 16 + g * 4 + r;
                Of[(size_t)m * HD + o] = acc[mi][ni][r];
            }
        }
    }
}

// ---------------------------------------------------------------------------
// K2a: per (bh, i-block of 64): rowsum of exp(K.Q^T/8) over unmasked j ->
// invS[bh][i] = 1/rowsum. Also zero-fills dist's strict-upper tiles for this
// i-block. Raw barriers: stage(jt+1) AFTER the barrier -> full-tile cover.
// ---------------------------------------------------------------------------
__global__ __launch_bounds__(256, 4)
void rowsum_kernel(const bf16* __restrict__ Kh, const bf16* __restrict__ Qh,
                   float* __restrict__ invS, float* __restrict__ Dist)
{
    __shared__ alignas(16) bf16 Kl[64 * 64];
    __shared__ alignas(16) bf16 Ql[2][64 * 64];
    const int tid = threadIdx.x, lane = tid & 63, w = tid >> 6;
    const int g = lane >> 4, ln = lane & 15;
    const int ib = 15 - (int)blockIdx.x, bh = blockIdx.y;   // heavy blocks first
    const char* Kp = (const char*)(Kh + ((size_t)bh * SQ + ib * 64) * DKK);
    const char* Qp = (const char*)(Qh + (size_t)bh * SQ * DKK);
    float* Dp = Dist + (size_t)bh * SQ * SQ;

    stage64(Kp, 128, (char*)Kl, w, lane);
    stage64(Qp, 128, (char*)Ql[0], w, lane);
    vm_bar();

    const int arow = w * 16 + ln;
    const int asw  = (arow ^ (arow >> 3)) & 7;
    const bf16x8_t ak0 = *(const bf16x8_t*)&Kl[arow * 64 + ((g ^ asw) << 3)];
    const bf16x8_t ak1 = *(const bf16x8_t*)&Kl[arow * 64 + (((4 + g) ^ asw) << 3)];
    const int irow = ib * 64 + w * 16 + g * 4;

    float lsum[4] = {0.f, 0.f, 0.f, 0.f};
    for (int jt = 0; jt <= ib; ++jt) {
        const int buf = jt & 1;
        if (jt > 0) vm_bar();                       // Q(jt) ready: full-tile cover
        if (jt < ib)
            stage64(Qp + (size_t)(jt + 1) * 8192, 128, (char*)Ql[buf ^ 1], w, lane);
#pragma unroll
        for (int nf = 0; nf < 4; ++nf) {
            const int brow = nf * 16 + ln;
            const int bsw  = (brow ^ (brow >> 3)) & 7;
            bf16x8_t b0 = *(const bf16x8_t*)&Ql[buf][brow * 64 + ((g ^ bsw) << 3)];
            bf16x8_t b1 = *(const bf16x8_t*)&Ql[buf][brow * 64 + (((4 + g) ^ bsw) << 3)];
            f32x4_t a = (f32x4_t){0.f, 0.f, 0.f, 0.f};
            __builtin_amdgcn_s_setprio(1);
            a = __builtin_amdgcn_mfma_f32_16x16x32_bf16(ak0, b0, a, 0, 0, 0);
            a = __builtin_amdgcn_mfma_f32_16x16x32_bf16(ak1, b1, a, 0, 0, 0);
            __builtin_amdgcn_s_setprio(0);
            const int j = jt * 64 + nf * 16 + ln;
#pragma unroll
            for (int r = 0; r < 4; ++r)
                lsum[r] += (j <= irow + r) ? __expf(a[r] * 0.125f) : 0.f;
        }
    }
#pragma unroll
    for (int r = 0; r < 4; ++r) {
        float p = lsum[r];
        p += __shfl_xor(p, 1);
        p += __shfl_xor(p, 2);
        p += __shfl_xor(p, 4);
        p += __shfl_xor(p, 8);
        lsum[r] = p;
    }
    if (ln == 0) {
#pragma unroll
        for (int r = 0; r < 4; ++r)
            invS[(size_t)bh * SQ + irow + r] = 1.f / lsum[r];
    }
    // zero-fill strict-upper tiles of this i-block (fire-and-forget stores)
    const f32x4_t zero4 = (f32x4_t){0.f, 0.f, 0.f, 0.f};
    for (int jt = ib + 1; jt < 16; ++jt) {
#pragma unroll
        for (int q = 0; q < 4; ++q) {
            const int cid = q * 256 + tid;
            const int row = cid >> 4, ch = cid & 15;
            *(f32x4_t*)(Dp + (size_t)(ib * 64 + row) * SQ + jt * 64 + ch * 4) = zero4;
        }
    }
}

// ---------------------------------------------------------------------------
// K2b (fused): per (bh, j-block of 64), for i-tiles it=jb..15:
//   recompute scores (Q frags in regs, K staged), dist = exp(s)*invS[i] ->
//   f32 stores straight from registers; bf16 into dT (dbuf, in-LDS
//   transpose); PV MFMA with pre-transposed V.
// B1 = vm drain (full-tile-covered), B2 = LDS-only (prefetch + stores stay
// in flight). 50 KB LDS -> 3 blocks/CU.
// ---------------------------------------------------------------------------
__global__ __launch_bounds__(256, 3)
void dist_pv_kernel(const bf16* __restrict__ Kh, const bf16* __restrict__ Qh,
                    const bf16* __restrict__ Vt, const float* __restrict__ invS,
                    float* __restrict__ Dist, bf16* __restrict__ att4)
{
    __shared__ alignas(16) bf16 Kl[2][64 * 64];   // 16 KB
    __shared__ alignas(16) bf16 Vl[2][64 * 64];   // 16 KB
    __shared__ alignas(16) bf16 dT[2][64 * 72];   // 18 KB; dT[0] doubles as Ql
    const int tid = threadIdx.x, lane = tid & 63, w = tid >> 6;
    const int g = lane >> 4, ln = lane & 15;
    const int jb = blockIdx.x, bh = blockIdx.y;   // jb=0 heaviest, first
    const char* Kp = (const char*)(Kh + (size_t)bh * SQ * DKK);
    const char* Qp = (const char*)(Qh + (size_t)bh * SQ * DKK);
    const char* Vp = (const char*)(Vt + (size_t)bh * DKK * SQ);
    float* Dp = Dist + (size_t)bh * SQ * SQ;
    const float* ivp = invS + (size_t)bh * SQ;

    // prologue: Q block -> dT[0] (flat 64x64), first K/V tile -> buf 0
    stage64(Qp + (size_t)jb * 8192, 128, (char*)&dT[0][0], w, lane);
    stage64(Kp + (size_t)jb * 8192, 128, (char*)&Kl[0][0], w, lane);
    stage64(Vp + (size_t)jb * 128, 2048, (char*)&Vl[0][0], w, lane);
    vm_bar();

    bf16x8_t bq[4][2];
    {
        const bf16* Qlp = &dT[0][0];
#pragma unroll
        for (int nf = 0; nf < 4; ++nf) {
            const int brow = nf * 16 + ln;
            const int bsw  = (brow ^ (brow >> 3)) & 7;
            bq[nf][0] = *(const bf16x8_t*)&Qlp[brow * 64 + ((g ^ bsw) << 3)];
            bq[nf][1] = *(const bf16x8_t*)&Qlp[brow * 64 + (((4 + g) ^ bsw) << 3)];
        }
    }

    const int arow = w * 16 + ln;
    const int asw  = (arow ^ (arow >> 3)) & 7;
    f32x4_t accPV[4];
#pragma unroll
    for (int nf = 0; nf < 4; ++nf) accPV[nf] = (f32x4_t){0.f, 0.f, 0.f, 0.f};

    for (int it = jb; it < 16; ++it) {
        const int cb = (it - jb) & 1;
        // B1: K/V(it) drained; all waves past PV(it-1); orders prologue
        //     bq-reads vs first dT write.
        vm_bar();
        if (it < 15) {
            stage64(Kp + (size_t)(it + 1) * 8192, 128, (char*)&Kl[cb ^ 1][0], w, lane);
            stage64(Vp + (size_t)(it + 1) * 128, 2048, (char*)&Vl[cb ^ 1][0], w, lane);
        }
        const int i0 = it * 64 + w * 16 + g * 4;
        float iv[4];
#pragma unroll
        for (int r = 0; r < 4; ++r) iv[r] = ivp[i0 + r];

        const bf16x8_t ak0 = *(const bf16x8_t*)&Kl[cb][arow * 64 + ((g ^ asw) << 3)];
        const bf16x8_t ak1 = *(const bf16x8_t*)&Kl[cb][arow * 64 + (((4 + g) ^ asw) << 3)];
#pragma unroll
        for (int nf = 0; nf < 4; ++nf) {
            f32x4_t a = (f32x4_t){0.f, 0.f, 0.f, 0.f};
            __builtin_amdgcn_s_setprio(1);
            a = __builtin_amdgcn_mfma_f32_16x16x32_bf16(ak0, bq[nf][0], a, 0, 0, 0);
            a = __builtin_amdgcn_mfma_f32_16x16x32_bf16(ak1, bq[nf][1], a, 0, 0, 0);
            __builtin_amdgcn_s_setprio(0);
            const int jl = nf * 16 + ln;
            const int j  = jb * 64 + jl;
            bf16x4_t pk;
#pragma unroll
            for (int r = 0; r < 4; ++r) {
                const float e = (j <= i0 + r) ? __expf(a[r] * 0.125f) * iv[r] : 0.f;
                Dp[(size_t)(i0 + r) * SQ + j] = e;   // 64B-aligned segment store
                pk[r] = (__bf16)e;
            }
            *(bf16x4_t*)&dT[cb][jl * 72 + ((w * 16 + g * 4) ^ (((jl >> 3) & 7) << 3))] = pk;
        }
        lgkm_bar();   // B2: dT[cb] visible; vmem stays in flight
#pragma unroll
        for (int kk = 0; kk < 2; ++kk) {
            const int abase = (kk * 32 + g * 8) ^ (((arow >> 3) & 7) << 3);
            const bf16x8_t a = *(const bf16x8_t*)&dT[cb][arow * 72 + abase];
            __builtin_amdgcn_s_setprio(1);
#pragma unroll
            for (int nf = 0; nf < 4; ++nf) {
                const int brow = nf * 16 + ln;
                const int bsw  = (brow ^ (brow >> 3)) & 7;
                const bf16x8_t b =
                    *(const bf16x8_t*)&Vl[cb][brow * 64 + (((kk * 4 + g) ^ bsw) << 3)];
                accPV[nf] = __builtin_amdgcn_mfma_f32_16x16x32_bf16(a, b, accPV[nf], 0, 0, 0);
            }
            __builtin_amdgcn_s_setprio(0);
        }
    }

    const int h = bh >> 3, b = bh & 7;
#pragma unroll
    for (int nf = 0; nf < 4; ++nf) {
#pragma unroll
        for (int r = 0; r < 4; ++r) {
            const int j = jb * 64 + w * 16 + g * 4 + r;
            att4[(size_t)(j * 8 + b) * HD + h * 64 + nf * 16 + ln] =
                __float2bfloat16(accPV[nf][r]);
        }
    }
}

// ---------------------------------------------------------------------------
extern "C" void kernel_launch(void* const* d_in, const int* in_sizes, int n_in,
                              void* d_out, int out_size, void* d_ws, size_t ws_size,
                              hipStream_t stream)
{
    const float* value = (const float*)d_in[0];
    const float* key_  = (const float*)d_in[1];
    const float* query = (const float*)d_in[2];
    const float* Wq    = (const float*)d_in[3];
    const float* Wk    = (const float*)d_in[4];
    const float* Wv    = (const float*)d_in[5];
    const float* Wo    = (const float*)d_in[6];

    float* out  = (float*)d_out;                       // (S,B,H) f32
    float* dist = out + (size_t)SQ * NB * HD;          // (128,1024,1024) f32
    float* invS = out;   // scratch: 512 KB in out region, consumed before K4

    // bf16 pre-convert scratch parked in the dist region — ONLY buffers whose
    // last use (K1) precedes the first dist write (K2a/K2b). Wo stays f32 and
    // is cvt-staged inside K4 (it must outlive the dist writes).
    bf16* qb  = (bf16*)dist;
    bf16* kb  = qb  + (size_t)SQ * NB * HD;
    bf16* vb  = kb  + (size_t)SQ * NB * HD;
    bf16* wqb = vb  + (size_t)SQ * NB * HD;
    bf16* wkb = wqb + (size_t)HD * HD;
    bf16* wvb = wkb + (size_t)HD * HD;

    char* ws   = (char*)d_ws;
    bf16* Qh   = (bf16*)(ws);                          // 16 MB each
    bf16* Kh   = (bf16*)(ws + (size_t)16 * 1024 * 1024);
    bf16* Vt   = (bf16*)(ws + (size_t)32 * 1024 * 1024);   // V transposed [bh][d][s]
    bf16* att4 = (bf16*)(ws + (size_t)48 * 1024 * 1024);

    dim3 blk(256);
    // K0: f32 -> bf16 (inputs + QKV weights)
    cvt_kernel<<<dim3(4096, 1, 3), blk, 0, stream>>>(query, key_, value, qb, kb, vb);
    cvt_kernel<<<dim3(512, 1, 3), blk, 0, stream>>>(Wq, Wk, Wv, wqb, wkb, wvb);
    // K1: projections (all-bf16) -> head-major Qh/Kh + transposed Vt
    gemm_bb<<<dim3(8, 64, 3), blk, 0, stream>>>(
        qb, kb, vb, wqb, wkb, wvb, Qh, Kh, Vt);
    // K2a: softmax denominators -> invS; zero-fill dist upper triangle
    rowsum_kernel<<<dim3(16, 128), blk, 0, stream>>>(Kh, Qh, invS, dist);
    // K2b: fused dist write (output 2) + PV -> bf16 att4
    dist_pv_kernel<<<dim3(16, 128), blk, 0, stream>>>(Kh, Qh, Vt, invS, dist, att4);
    // K4: out = att4 @ Wo^T -> f32 d_out (output 1)
    gemm_k4<<<dim3(8, 64), blk, 0, stream>>>(att4, Wo, out);
}